// Round 1
// baseline (726.332 us; speedup 1.0000x reference)
//
#include <hip/hip_runtime.h>

#define DD 128
#define NTILE 32

// ---------------- CSR build ----------------
__global__ void count_deg(const int* __restrict__ dst, int* __restrict__ counts, int e) {
  int t = blockIdx.x * 256 + threadIdx.x;
  if (t < e) atomicAdd(&counts[dst[t]], 1);
}

// exclusive scan of counts within 1024-element blocks; per-block totals to partials
__global__ void scan_block(const int* __restrict__ counts, int* __restrict__ rs,
                           int* __restrict__ partials, int n) {
  __shared__ int wsum[4];
  int tid = threadIdx.x;
  int base = blockIdx.x * 1024 + tid * 4;
  int v0 = (base + 0 < n) ? counts[base + 0] : 0;
  int v1 = (base + 1 < n) ? counts[base + 1] : 0;
  int v2 = (base + 2 < n) ? counts[base + 2] : 0;
  int v3 = (base + 3 < n) ? counts[base + 3] : 0;
  int tsum = v0 + v1 + v2 + v3;
  int incl = tsum;
  int lane = tid & 63;
#pragma unroll
  for (int off = 1; off < 64; off <<= 1) {
    int u = __shfl_up(incl, off);
    if (lane >= off) incl += u;
  }
  if (lane == 63) wsum[tid >> 6] = incl;
  __syncthreads();
  int woff = 0;
  for (int w = 0; w < (tid >> 6); ++w) woff += wsum[w];
  int ex = woff + incl - tsum;  // exclusive prefix of this thread within block
  if (base + 0 < n) rs[base + 0] = ex;
  ex += v0;
  if (base + 1 < n) rs[base + 1] = ex;
  ex += v1;
  if (base + 2 < n) rs[base + 2] = ex;
  ex += v2;
  if (base + 3 < n) rs[base + 3] = ex;
  if (tid == 255) partials[blockIdx.x] = woff + incl;  // block total
}

// exclusive scan of <=64 block partials (in place)
__global__ void scan_partials_k(int* partials, int nb) {
  int lane = threadIdx.x;
  int v = (lane < nb) ? partials[lane] : 0;
  int incl = v;
#pragma unroll
  for (int off = 1; off < 64; off <<= 1) {
    int u = __shfl_up(incl, off);
    if (lane >= off) incl += u;
  }
  if (lane < nb) partials[lane] = incl - v;
}

__global__ void scan_finalize(int* __restrict__ rs, const int* __restrict__ partials,
                              int* __restrict__ cursor, int n, int e) {
  int i = blockIdx.x * 256 + threadIdx.x;
  if (i < n) {
    int r = rs[i] + partials[i >> 10];
    rs[i] = r;
    cursor[i] = r;
  }
  if (i == 0) rs[n] = e;
}

__global__ void fill_csr(const int* __restrict__ src, const int* __restrict__ dst,
                         int* __restrict__ cursor, int* __restrict__ ssrc, int e) {
  int t = blockIdx.x * 256 + threadIdx.x;
  if (t < e) {
    int d = dst[t];
    int p = atomicAdd(&cursor[d], 1);
    ssrc[p] = src[t];
  }
}

// ---------------- aggregation: z = h + sum_{j->i} h[j]  (one wave per node) ----------------
__global__ __launch_bounds__(256) void gather_z(const float* __restrict__ h,
                                                const int* __restrict__ rs,
                                                const int* __restrict__ ssrc,
                                                float* __restrict__ z, int n) {
  int node = blockIdx.x * 4 + (threadIdx.x >> 6);
  if (node >= n) return;
  int lane = threadIdx.x & 63;
  const float2* h2 = (const float2*)h;
  int s0 = rs[node], s1 = rs[node + 1];
  float2 acc = h2[(size_t)node * 64 + lane];  // (1+eps)*x_i with eps=0
  int t = s0;
  for (; t + 3 < s1; t += 4) {
    int sa = ssrc[t + 0], sb = ssrc[t + 1], sc = ssrc[t + 2], sd = ssrc[t + 3];
    float2 va = h2[(size_t)sa * 64 + lane];
    float2 vb = h2[(size_t)sb * 64 + lane];
    float2 vc = h2[(size_t)sc * 64 + lane];
    float2 vd = h2[(size_t)sd * 64 + lane];
    acc.x += va.x + vb.x + vc.x + vd.x;
    acc.y += va.y + vb.y + vc.y + vd.y;
  }
  for (; t < s1; ++t) {
    int s = ssrc[t];
    float2 v = h2[(size_t)s * 64 + lane];
    acc.x += v.x;
    acc.y += v.y;
  }
  ((float2*)z)[(size_t)node * 64 + lane] = acc;
}

// ---------------- fused MLP: hout = relu(z@W1+b1)@W2+b2 (in-place safe per 32-row tile) ----
__global__ __launch_bounds__(256, 2) void mlp_kernel(
    const float* __restrict__ zin, const float* __restrict__ W1, const float* __restrict__ b1,
    const float* __restrict__ W2, const float* __restrict__ b2, float* __restrict__ hout,
    int n) {
  __shared__ float Ws[64][DD];        // 32 KB, K-chunk of weights
  __shared__ float zs[NTILE][DD + 4]; // padded: scalar col reads conflict-free, f4 aligned
  __shared__ float hs[NTILE][DD + 4];
  int tid = threadIdx.x;
  int node0 = blockIdx.x * NTILE;
  int jq = tid & 31;  // output cols j = jq*4 .. +3
  int nq = tid >> 5;  // rows n = nq*4 .. +3

  // stage z tile (coalesced float4 loads)
  for (int i = tid; i < NTILE * DD / 4; i += 256) {
    int nn = i >> 5;
    int dq = i & 31;
    float4 v = make_float4(0.f, 0.f, 0.f, 0.f);
    if (node0 + nn < n) v = *(const float4*)&zin[(size_t)(node0 + nn) * DD + dq * 4];
    *(float4*)&zs[nn][dq * 4] = v;
  }

  float acc[4][4];
#pragma unroll
  for (int b = 0; b < 4; ++b) {
    float bb = b1[jq * 4 + b];
#pragma unroll
    for (int a = 0; a < 4; ++a) acc[a][b] = bb;
  }

  // matmul 1
  for (int kc = 0; kc < 2; ++kc) {
    __syncthreads();  // covers z staging (kc=0) and Ws reuse (kc=1)
    for (int i = tid; i < 64 * DD / 4; i += 256) {
      int r = i >> 5;
      int c = (i & 31) * 4;
      *(float4*)&Ws[r][c] = *(const float4*)&W1[(size_t)(kc * 64 + r) * DD + c];
    }
    __syncthreads();
    for (int k = 0; k < 64; ++k) {
      float4 wv = *(const float4*)&Ws[k][jq * 4];
      int kk = kc * 64 + k;
#pragma unroll
      for (int a = 0; a < 4; ++a) {
        float zv = zs[nq * 4 + a][kk];
        acc[a][0] += zv * wv.x;
        acc[a][1] += zv * wv.y;
        acc[a][2] += zv * wv.z;
        acc[a][3] += zv * wv.w;
      }
    }
  }

  // relu -> hs
#pragma unroll
  for (int a = 0; a < 4; ++a) {
    float4 hv;
    hv.x = fmaxf(acc[a][0], 0.f);
    hv.y = fmaxf(acc[a][1], 0.f);
    hv.z = fmaxf(acc[a][2], 0.f);
    hv.w = fmaxf(acc[a][3], 0.f);
    *(float4*)&hs[nq * 4 + a][jq * 4] = hv;
  }

#pragma unroll
  for (int b = 0; b < 4; ++b) {
    float bb = b2[jq * 4 + b];
#pragma unroll
    for (int a = 0; a < 4; ++a) acc[a][b] = bb;
  }

  // matmul 2
  for (int kc = 0; kc < 2; ++kc) {
    __syncthreads();  // hs writes visible + Ws reads of prev chunk done
    for (int i = tid; i < 64 * DD / 4; i += 256) {
      int r = i >> 5;
      int c = (i & 31) * 4;
      *(float4*)&Ws[r][c] = *(const float4*)&W2[(size_t)(kc * 64 + r) * DD + c];
    }
    __syncthreads();
    for (int k = 0; k < 64; ++k) {
      float4 wv = *(const float4*)&Ws[k][jq * 4];
      int kk = kc * 64 + k;
#pragma unroll
      for (int a = 0; a < 4; ++a) {
        float hv = hs[nq * 4 + a][kk];
        acc[a][0] += hv * wv.x;
        acc[a][1] += hv * wv.y;
        acc[a][2] += hv * wv.z;
        acc[a][3] += hv * wv.w;
      }
    }
  }

  // write out
#pragma unroll
  for (int a = 0; a < 4; ++a) {
    int nn = node0 + nq * 4 + a;
    if (nn < n) {
      float4 o = make_float4(acc[a][0], acc[a][1], acc[a][2], acc[a][3]);
      *(float4*)&hout[(size_t)nn * DD + jq * 4] = o;
    }
  }
}

// ---------------- classifier: logits = h @ Wc + bc ----------------
__global__ __launch_bounds__(256) void classifier_k(const float* __restrict__ h,
                                                    const float* __restrict__ Wc,
                                                    const float* __restrict__ bc,
                                                    float* __restrict__ out, int n) {
  __shared__ float wcs[DD * 16];
  for (int i = threadIdx.x; i < DD * 16; i += 256) wcs[i] = Wc[i];
  __syncthreads();
  int t = blockIdx.x * 256 + threadIdx.x;
  int node = t >> 4, c = t & 15;
  if (node >= n) return;
  float acc = bc[c];
  const float* hr = h + (size_t)node * DD;
#pragma unroll 8
  for (int k = 0; k < DD; ++k) acc += hr[k] * wcs[k * 16 + c];
  out[(size_t)node * 16 + c] = acc;
}

extern "C" void kernel_launch(void* const* d_in, const int* in_sizes, int n_in,
                              void* d_out, int out_size, void* d_ws, size_t ws_size,
                              hipStream_t stream) {
  const float* x = (const float*)d_in[0];
  const int* ei = (const int*)d_in[1];
  const float* W1 = (const float*)d_in[2];
  const float* b1 = (const float*)d_in[3];
  const float* W2 = (const float*)d_in[4];
  const float* b2 = (const float*)d_in[5];
  const float* Wc = (const float*)d_in[6];
  const float* bc = (const float*)d_in[7];

  const int N = in_sizes[0] / DD;
  const int E = in_sizes[1] / 2;
  const int* src = ei;
  const int* dst = ei + E;

  float* outp = (float*)d_out;
  float* h_final = outp;                       // N*DD
  float* logits = outp + (size_t)N * DD;       // N*16

  char* ws = (char*)d_ws;
  size_t off = 0;
  auto alloc = [&](size_t bytes) {
    char* p = ws + off;
    off = (off + bytes + 255) & ~(size_t)255;
    return p;
  };
  float* h1 = (float*)alloc((size_t)N * DD * 4);
  float* h2 = (float*)alloc((size_t)N * DD * 4);
  int* rs = (int*)alloc((size_t)(N + 1) * 4);
  int* cursor = (int*)alloc((size_t)N * 4);
  int* counts = (int*)alloc((size_t)N * 4);
  int* partials = (int*)alloc(64 * 4);
  int* ssrc = (int*)alloc((size_t)E * 4);

  const int nbScan = (N + 1023) / 1024;  // 49 (<=64 required by scan_partials_k)

  hipMemsetAsync(counts, 0, (size_t)N * 4, stream);
  count_deg<<<(E + 255) / 256, 256, 0, stream>>>(dst, counts, E);
  scan_block<<<nbScan, 256, 0, stream>>>(counts, rs, partials, N);
  scan_partials_k<<<1, 64, 0, stream>>>(partials, nbScan);
  scan_finalize<<<(N + 255) / 256, 256, 0, stream>>>(rs, partials, cursor, N, E);
  fill_csr<<<(E + 255) / 256, 256, 0, stream>>>(src, dst, cursor, ssrc, E);

  const int gGather = (N + 3) / 4;
  const int gMlp = (N + NTILE - 1) / NTILE;

  // layer 0: x -> h1
  gather_z<<<gGather, 256, 0, stream>>>(x, rs, ssrc, h1, N);
  mlp_kernel<<<gMlp, 256, 0, stream>>>(h1, W1, b1, W2, b2, h1, N);
  // layer 1: h1 -> h2
  gather_z<<<gGather, 256, 0, stream>>>(h1, rs, ssrc, h2, N);
  mlp_kernel<<<gMlp, 256, 0, stream>>>(h2, W1 + DD * DD, b1 + DD, W2 + DD * DD, b2 + DD, h2, N);
  // layer 2: h2 -> d_out (h region)
  gather_z<<<gGather, 256, 0, stream>>>(h2, rs, ssrc, h_final, N);
  mlp_kernel<<<gMlp, 256, 0, stream>>>(h_final, W1 + 2 * DD * DD, b1 + 2 * DD,
                                       W2 + 2 * DD * DD, b2 + 2 * DD, h_final, N);

  classifier_k<<<(N * 16 + 255) / 256, 256, 0, stream>>>(h_final, Wc, bc, logits, N);
}

// Round 2
// 450.533 us; speedup vs baseline: 1.6122x; 1.6122x over previous
//
#include <hip/hip_runtime.h>

#define DD 128
#define NTILE 32
#define CHUNK 6144   // edges per block in S1/S3
#define NBMAX 512    // max buckets (N <= 65536)
#define SCAP 8192    // per-bucket LDS staging capacity (mean ~4092, 64 sigma headroom)

// ---------- bf16 helpers ----------
__device__ __forceinline__ unsigned bf16rne(float f) {
  unsigned u = __float_as_uint(f);
  return (u + 0x7FFFu + ((u >> 16) & 1u)) >> 16;
}
__device__ __forceinline__ unsigned packbf(float lo, float hi) {
  return bf16rne(lo) | (bf16rne(hi) << 16);
}
__device__ __forceinline__ float bflo(unsigned v) { return __uint_as_float(v << 16); }
__device__ __forceinline__ float bfhi(unsigned v) { return __uint_as_float(v & 0xFFFF0000u); }

// ---------- inclusive block scan over LDS array (256 threads, nb <= 512) ----------
__device__ void block_scan_incl(int* cnt, int* inc, int nb, int tid) {
  for (int i = tid; i < nb; i += 256) inc[i] = cnt[i];
  __syncthreads();
  for (int d = 1; d < nb; d <<= 1) {
    int i0 = tid, i1 = tid + 256;
    int v0 = 0, v1 = 0;
    if (i0 < nb && i0 >= d) v0 = inc[i0 - d];
    if (i1 < nb && i1 >= d) v1 = inc[i1 - d];
    __syncthreads();
    if (i0 < nb) inc[i0] += v0;
    if (i1 < nb) inc[i1] += v1;
    __syncthreads();
  }
}

// ---------- S1: bucket histogram (bucket = dst >> 7) ----------
__global__ __launch_bounds__(256) void s1_hist(const int* __restrict__ dst,
                                               int* __restrict__ bucketCount, int e) {
  __shared__ int h[NBMAX];
  int tid = threadIdx.x;
  for (int i = tid; i < NBMAX; i += 256) h[i] = 0;
  __syncthreads();
  int i0 = blockIdx.x * CHUNK;
  int i1 = min(i0 + CHUNK, e);
  for (int i = i0 + tid; i < i1; i += 256) atomicAdd(&h[dst[i] >> 7], 1);
  __syncthreads();
  for (int i = tid; i < NBMAX; i += 256)
    if (h[i]) atomicAdd(&bucketCount[i], h[i]);
}

// ---------- S2: scan bucket counts -> bucketOff, init cursors, rs[N]=E ----------
__global__ __launch_bounds__(256) void s2_scan(const int* __restrict__ bucketCount,
                                               int* __restrict__ bucketOff,
                                               int* __restrict__ gCursor,
                                               int* __restrict__ rs, int nb, int n, int e) {
  __shared__ int cnt[NBMAX], inc[NBMAX];
  int tid = threadIdx.x;
  for (int i = tid; i < nb; i += 256) cnt[i] = bucketCount[i];
  __syncthreads();
  block_scan_incl(cnt, inc, nb, tid);
  for (int i = tid; i < nb; i += 256) {
    int off = inc[i] - cnt[i];
    bucketOff[i] = off;
    gCursor[i] = off;
  }
  if (tid == 0) { bucketOff[nb] = e; rs[n] = e; }
}

// ---------- S3: block-local grouping + coalesced bucket scatter of packed pairs ----------
__global__ __launch_bounds__(256) void s3_scatter(const int* __restrict__ src,
                                                  const int* __restrict__ dst,
                                                  int* __restrict__ gCursor,
                                                  unsigned int* __restrict__ bucketed,
                                                  int e, int nb) {
  __shared__ int cnt[NBMAX], inc[NBMAX], base[NBMAX], cur[NBMAX];
  __shared__ unsigned int pairs[CHUNK];
  int tid = threadIdx.x;
  for (int i = tid; i < nb; i += 256) cnt[i] = 0;
  __syncthreads();
  int i0 = blockIdx.x * CHUNK;
  int i1 = min(i0 + CHUNK, e);
  for (int i = i0 + tid; i < i1; i += 256) atomicAdd(&cnt[dst[i] >> 7], 1);
  __syncthreads();
  block_scan_incl(cnt, inc, nb, tid);
  for (int b = tid; b < nb; b += 256) {
    int c = cnt[b];
    base[b] = c ? atomicAdd(&gCursor[b], c) : 0;
    cur[b] = inc[b] - c;  // local exclusive offset
  }
  __syncthreads();
  for (int i = i0 + tid; i < i1; i += 256) {
    int d = dst[i];
    int p = atomicAdd(&cur[d >> 7], 1);
    pairs[p] = (unsigned)d | ((unsigned)src[i] << 16);  // both < 65536
  }
  __syncthreads();
  int m = i1 - i0;
  for (int i = tid; i < m; i += 256) {
    unsigned w = pairs[i];
    int b = (int)(w & 0xFFFFu) >> 7;
    bucketed[base[b] + (i - (inc[b] - cnt[b]))] = w;  // coalesced runs per bucket
  }
}

// ---------- S4: per-bucket node-level fill; emits rs[] and u16 ssrc ----------
__global__ __launch_bounds__(256) void s4_fill(const unsigned int* __restrict__ bucketed,
                                               const int* __restrict__ bucketOff,
                                               int* __restrict__ rs,
                                               unsigned short* __restrict__ ssrc, int n) {
  __shared__ int cnt[128], inc[128], cur[128];
  __shared__ unsigned short outb[SCAP];
  int b = blockIdx.x;
  int bo = bucketOff[b], b1 = bucketOff[b + 1];
  int len = b1 - bo;
  int tid = threadIdx.x;
  int n0 = b << 7;
  if (tid < 128) cnt[tid] = 0;
  __syncthreads();
  for (int i = tid; i < len; i += 256) atomicAdd(&cnt[bucketed[bo + i] & 127], 1);
  __syncthreads();
  if (tid < 128) inc[tid] = cnt[tid];
  __syncthreads();
  for (int d = 1; d < 128; d <<= 1) {
    int v = 0;
    if (tid < 128 && tid >= d) v = inc[tid - d];
    __syncthreads();
    if (tid < 128) inc[tid] += v;
    __syncthreads();
  }
  if (tid < 128) {
    int off = inc[tid] - cnt[tid];
    cur[tid] = off;
    int node = n0 + tid;
    if (node < n) rs[node] = bo + off;
  }
  __syncthreads();
  if (len <= SCAP) {
    for (int i = tid; i < len; i += 256) {
      unsigned w = bucketed[bo + i];
      int p = atomicAdd(&cur[w & 127], 1);
      outb[p] = (unsigned short)(w >> 16);
    }
    __syncthreads();
    for (int i = tid; i < len; i += 256) ssrc[bo + i] = outb[i];  // coalesced
  } else {  // safety fallback (statistically unreachable)
    for (int i = tid; i < len; i += 256) {
      unsigned w = bucketed[bo + i];
      int p = atomicAdd(&cur[w & 127], 1);
      ssrc[bo + p] = (unsigned short)(w >> 16);
    }
  }
}

// ---------- conv: f32 -> packed bf16x2 ----------
__global__ __launch_bounds__(256) void conv_bf16(const float* __restrict__ x,
                                                 unsigned int* __restrict__ hb, int n64) {
  int i = blockIdx.x * 256 + threadIdx.x;
  if (i < n64) {
    float2 v = ((const float2*)x)[i];
    hb[i] = packbf(v.x, v.y);
  }
}

// ---------- aggregation: z = hb_i + sum_{j->i} hb_j (f32 accum, one wave/node) ----------
__global__ __launch_bounds__(256) void gather_zb(const unsigned int* __restrict__ hb,
                                                 const int* __restrict__ rs,
                                                 const unsigned short* __restrict__ ssrc,
                                                 float* __restrict__ z, int n) {
  int node = blockIdx.x * 4 + (threadIdx.x >> 6);
  if (node >= n) return;
  int lane = threadIdx.x & 63;
  int s0 = rs[node], s1 = rs[node + 1];
  unsigned v = hb[(size_t)node * 64 + lane];
  float ax = bflo(v), ay = bfhi(v);
  int t = s0;
  for (; t + 3 < s1; t += 4) {
    int sa = ssrc[t], sb = ssrc[t + 1], sc = ssrc[t + 2], sd = ssrc[t + 3];
    unsigned va = hb[(size_t)sa * 64 + lane];
    unsigned vb = hb[(size_t)sb * 64 + lane];
    unsigned vc = hb[(size_t)sc * 64 + lane];
    unsigned vd = hb[(size_t)sd * 64 + lane];
    ax += bflo(va) + bflo(vb) + bflo(vc) + bflo(vd);
    ay += bfhi(va) + bfhi(vb) + bfhi(vc) + bfhi(vd);
  }
  for (; t < s1; ++t) {
    unsigned vv = hb[(size_t)ssrc[t] * 64 + lane];
    ax += bflo(vv);
    ay += bfhi(vv);
  }
  ((float2*)z)[(size_t)node * 64 + lane] = make_float2(ax, ay);
}

// ---------- fused MLP (f32): optional f32 and/or bf16 outputs ----------
__global__ __launch_bounds__(256, 2) void mlp_kernel(
    const float* __restrict__ zin, const float* __restrict__ W1, const float* __restrict__ b1,
    const float* __restrict__ W2, const float* __restrict__ b2,
    float* __restrict__ fout, unsigned int* __restrict__ hbout, int n) {
  __shared__ float Ws[64][DD];
  __shared__ float zs[NTILE][DD + 4];
  __shared__ float hs[NTILE][DD + 4];
  int tid = threadIdx.x;
  int node0 = blockIdx.x * NTILE;
  int jq = tid & 31;
  int nq = tid >> 5;

  for (int i = tid; i < NTILE * DD / 4; i += 256) {
    int nn = i >> 5;
    int dq = i & 31;
    float4 v = make_float4(0.f, 0.f, 0.f, 0.f);
    if (node0 + nn < n) v = *(const float4*)&zin[(size_t)(node0 + nn) * DD + dq * 4];
    *(float4*)&zs[nn][dq * 4] = v;
  }

  float acc[4][4];
#pragma unroll
  for (int b = 0; b < 4; ++b) {
    float bb = b1[jq * 4 + b];
#pragma unroll
    for (int a = 0; a < 4; ++a) acc[a][b] = bb;
  }

  for (int kc = 0; kc < 2; ++kc) {
    __syncthreads();
    for (int i = tid; i < 64 * DD / 4; i += 256) {
      int r = i >> 5;
      int c = (i & 31) * 4;
      *(float4*)&Ws[r][c] = *(const float4*)&W1[(size_t)(kc * 64 + r) * DD + c];
    }
    __syncthreads();
    for (int k = 0; k < 64; ++k) {
      float4 wv = *(const float4*)&Ws[k][jq * 4];
      int kk = kc * 64 + k;
#pragma unroll
      for (int a = 0; a < 4; ++a) {
        float zv = zs[nq * 4 + a][kk];
        acc[a][0] += zv * wv.x;
        acc[a][1] += zv * wv.y;
        acc[a][2] += zv * wv.z;
        acc[a][3] += zv * wv.w;
      }
    }
  }

#pragma unroll
  for (int a = 0; a < 4; ++a) {
    float4 hv;
    hv.x = fmaxf(acc[a][0], 0.f);
    hv.y = fmaxf(acc[a][1], 0.f);
    hv.z = fmaxf(acc[a][2], 0.f);
    hv.w = fmaxf(acc[a][3], 0.f);
    *(float4*)&hs[nq * 4 + a][jq * 4] = hv;
  }

#pragma unroll
  for (int b = 0; b < 4; ++b) {
    float bb = b2[jq * 4 + b];
#pragma unroll
    for (int a = 0; a < 4; ++a) acc[a][b] = bb;
  }

  for (int kc = 0; kc < 2; ++kc) {
    __syncthreads();
    for (int i = tid; i < 64 * DD / 4; i += 256) {
      int r = i >> 5;
      int c = (i & 31) * 4;
      *(float4*)&Ws[r][c] = *(const float4*)&W2[(size_t)(kc * 64 + r) * DD + c];
    }
    __syncthreads();
    for (int k = 0; k < 64; ++k) {
      float4 wv = *(const float4*)&Ws[k][jq * 4];
      int kk = kc * 64 + k;
#pragma unroll
      for (int a = 0; a < 4; ++a) {
        float hv = hs[nq * 4 + a][kk];
        acc[a][0] += hv * wv.x;
        acc[a][1] += hv * wv.y;
        acc[a][2] += hv * wv.z;
        acc[a][3] += hv * wv.w;
      }
    }
  }

#pragma unroll
  for (int a = 0; a < 4; ++a) {
    int nn = node0 + nq * 4 + a;
    if (nn < n) {
      if (fout) {
        float4 o = make_float4(acc[a][0], acc[a][1], acc[a][2], acc[a][3]);
        *(float4*)&fout[(size_t)nn * DD + jq * 4] = o;
      }
      if (hbout) {
        uint2 p;
        p.x = packbf(acc[a][0], acc[a][1]);
        p.y = packbf(acc[a][2], acc[a][3]);
        *(uint2*)&hbout[(size_t)nn * 64 + jq * 2] = p;
      }
    }
  }
}

// ---------- classifier ----------
__global__ __launch_bounds__(256) void classifier_k(const float* __restrict__ h,
                                                    const float* __restrict__ Wc,
                                                    const float* __restrict__ bc,
                                                    float* __restrict__ out, int n) {
  __shared__ float wcs[DD * 16];
  for (int i = threadIdx.x; i < DD * 16; i += 256) wcs[i] = Wc[i];
  __syncthreads();
  int t = blockIdx.x * 256 + threadIdx.x;
  int node = t >> 4, c = t & 15;
  if (node >= n) return;
  float acc = bc[c];
  const float* hr = h + (size_t)node * DD;
#pragma unroll 8
  for (int k = 0; k < DD; ++k) acc += hr[k] * wcs[k * 16 + c];
  out[(size_t)node * 16 + c] = acc;
}

extern "C" void kernel_launch(void* const* d_in, const int* in_sizes, int n_in,
                              void* d_out, int out_size, void* d_ws, size_t ws_size,
                              hipStream_t stream) {
  const float* x = (const float*)d_in[0];
  const int* ei = (const int*)d_in[1];
  const float* W1 = (const float*)d_in[2];
  const float* b1 = (const float*)d_in[3];
  const float* W2 = (const float*)d_in[4];
  const float* b2 = (const float*)d_in[5];
  const float* Wc = (const float*)d_in[6];
  const float* bc = (const float*)d_in[7];

  const int N = in_sizes[0] / DD;
  const int E = in_sizes[1] / 2;
  const int* src = ei;
  const int* dst = ei + E;
  const int NB = (N + 127) >> 7;  // 391 buckets

  float* outp = (float*)d_out;
  float* h_final = outp;
  float* logits = outp + (size_t)N * DD;

  char* ws = (char*)d_ws;
  size_t off = 0;
  auto alloc = [&](size_t bytes) {
    char* p = ws + off;
    off = (off + bytes + 255) & ~(size_t)255;
    return p;
  };
  float* z = (float*)alloc((size_t)N * DD * 4);
  unsigned int* hb = (unsigned int*)alloc((size_t)N * 64 * 4);  // bf16x2 packed
  int* bucketCount = (int*)alloc(NBMAX * 4);
  int* bucketOff = (int*)alloc((NBMAX + 1) * 4);
  int* gCursor = (int*)alloc(NBMAX * 4);
  int* rs = (int*)alloc((size_t)(N + 1) * 4);
  unsigned int* bucketed = (unsigned int*)alloc((size_t)E * 4);
  unsigned short* ssrc = (unsigned short*)alloc((size_t)E * 2);

  const int gEdge = (E + CHUNK - 1) / CHUNK;  // 261
  const int gGather = (N + 3) / 4;
  const int gMlp = (N + NTILE - 1) / NTILE;

  // CSR build (coalesced, no float atomics)
  hipMemsetAsync(bucketCount, 0, NBMAX * 4, stream);
  s1_hist<<<gEdge, 256, 0, stream>>>(dst, bucketCount, E);
  s2_scan<<<1, 256, 0, stream>>>(bucketCount, bucketOff, gCursor, rs, NB, N, E);
  s3_scatter<<<gEdge, 256, 0, stream>>>(src, dst, gCursor, bucketed, E, NB);
  s4_fill<<<NB, 256, 0, stream>>>(bucketed, bucketOff, rs, ssrc, N);

  // x -> bf16
  conv_bf16<<<(N * 64 + 255) / 256, 256, 0, stream>>>(x, hb, N * 64);

  // layer 0
  gather_zb<<<gGather, 256, 0, stream>>>(hb, rs, ssrc, z, N);
  mlp_kernel<<<gMlp, 256, 0, stream>>>(z, W1, b1, W2, b2, nullptr, hb, N);
  // layer 1
  gather_zb<<<gGather, 256, 0, stream>>>(hb, rs, ssrc, z, N);
  mlp_kernel<<<gMlp, 256, 0, stream>>>(z, W1 + DD * DD, b1 + DD, W2 + DD * DD, b2 + DD,
                                       nullptr, hb, N);
  // layer 2 -> f32 output
  gather_zb<<<gGather, 256, 0, stream>>>(hb, rs, ssrc, z, N);
  mlp_kernel<<<gMlp, 256, 0, stream>>>(z, W1 + 2 * DD * DD, b1 + 2 * DD,
                                       W2 + 2 * DD * DD, b2 + 2 * DD, h_final, nullptr, N);

  classifier_k<<<(N * 16 + 255) / 256, 256, 0, stream>>>(h_final, Wc, bc, logits, N);
}

// Round 3
// 385.302 us; speedup vs baseline: 1.8851x; 1.1693x over previous
//
#include <hip/hip_runtime.h>

#define DD 128
#define CHUNK 6144   // edges per block in S1/S3
#define NBMAX 512    // max buckets (N <= 65536)
#define SCAP 8192    // per-bucket LDS staging capacity

typedef __attribute__((ext_vector_type(8))) short bf16x8;
typedef __attribute__((ext_vector_type(4))) float f32x4;

// ---------- bf16 helpers ----------
__device__ __forceinline__ unsigned bf16rne(float f) {
  unsigned u = __float_as_uint(f);
  return (u + 0x7FFFu + ((u >> 16) & 1u)) >> 16;
}
__device__ __forceinline__ unsigned packbf(float lo, float hi) {
  return bf16rne(lo) | (bf16rne(hi) << 16);
}
__device__ __forceinline__ float bflo(unsigned v) { return __uint_as_float(v << 16); }
__device__ __forceinline__ float bfhi(unsigned v) { return __uint_as_float(v & 0xFFFF0000u); }

// ---------- inclusive block scan over LDS array (256 threads, nb <= 512) ----------
__device__ void block_scan_incl(int* cnt, int* inc, int nb, int tid) {
  for (int i = tid; i < nb; i += 256) inc[i] = cnt[i];
  __syncthreads();
  for (int d = 1; d < nb; d <<= 1) {
    int i0 = tid, i1 = tid + 256;
    int v0 = 0, v1 = 0;
    if (i0 < nb && i0 >= d) v0 = inc[i0 - d];
    if (i1 < nb && i1 >= d) v1 = inc[i1 - d];
    __syncthreads();
    if (i0 < nb) inc[i0] += v0;
    if (i1 < nb) inc[i1] += v1;
    __syncthreads();
  }
}

// ---------- S1: bucket histogram (bucket = dst >> 7) ----------
__global__ __launch_bounds__(256) void s1_hist(const int* __restrict__ dst,
                                               int* __restrict__ bucketCount, int e) {
  __shared__ int h[NBMAX];
  int tid = threadIdx.x;
  for (int i = tid; i < NBMAX; i += 256) h[i] = 0;
  __syncthreads();
  int i0 = blockIdx.x * CHUNK;
  int i1 = min(i0 + CHUNK, e);
  for (int i = i0 + tid; i < i1; i += 256) atomicAdd(&h[dst[i] >> 7], 1);
  __syncthreads();
  for (int i = tid; i < NBMAX; i += 256)
    if (h[i]) atomicAdd(&bucketCount[i], h[i]);
}

// ---------- S2: scan bucket counts ----------
__global__ __launch_bounds__(256) void s2_scan(const int* __restrict__ bucketCount,
                                               int* __restrict__ bucketOff,
                                               int* __restrict__ gCursor,
                                               int* __restrict__ rs, int nb, int n, int e) {
  __shared__ int cnt[NBMAX], inc[NBMAX];
  int tid = threadIdx.x;
  for (int i = tid; i < nb; i += 256) cnt[i] = bucketCount[i];
  __syncthreads();
  block_scan_incl(cnt, inc, nb, tid);
  for (int i = tid; i < nb; i += 256) {
    int off = inc[i] - cnt[i];
    bucketOff[i] = off;
    gCursor[i] = off;
  }
  if (tid == 0) { bucketOff[nb] = e; rs[n] = e; }
}

// ---------- S3: block-local grouping + coalesced bucket scatter ----------
__global__ __launch_bounds__(256) void s3_scatter(const int* __restrict__ src,
                                                  const int* __restrict__ dst,
                                                  int* __restrict__ gCursor,
                                                  unsigned int* __restrict__ bucketed,
                                                  int e, int nb) {
  __shared__ int cnt[NBMAX], inc[NBMAX], base[NBMAX], cur[NBMAX];
  __shared__ unsigned int pairs[CHUNK];
  int tid = threadIdx.x;
  for (int i = tid; i < nb; i += 256) cnt[i] = 0;
  __syncthreads();
  int i0 = blockIdx.x * CHUNK;
  int i1 = min(i0 + CHUNK, e);
  for (int i = i0 + tid; i < i1; i += 256) atomicAdd(&cnt[dst[i] >> 7], 1);
  __syncthreads();
  block_scan_incl(cnt, inc, nb, tid);
  for (int b = tid; b < nb; b += 256) {
    int c = cnt[b];
    base[b] = c ? atomicAdd(&gCursor[b], c) : 0;
    cur[b] = inc[b] - c;
  }
  __syncthreads();
  for (int i = i0 + tid; i < i1; i += 256) {
    int d = dst[i];
    int p = atomicAdd(&cur[d >> 7], 1);
    pairs[p] = (unsigned)d | ((unsigned)src[i] << 16);
  }
  __syncthreads();
  int m = i1 - i0;
  for (int i = tid; i < m; i += 256) {
    unsigned w = pairs[i];
    int b = (int)(w & 0xFFFFu) >> 7;
    bucketed[base[b] + (i - (inc[b] - cnt[b]))] = w;
  }
}

// ---------- S4: per-bucket node-level fill; emits rs[] and u16 ssrc ----------
__global__ __launch_bounds__(256) void s4_fill(const unsigned int* __restrict__ bucketed,
                                               const int* __restrict__ bucketOff,
                                               int* __restrict__ rs,
                                               unsigned short* __restrict__ ssrc, int n) {
  __shared__ int cnt[128], inc[128], cur[128];
  __shared__ unsigned short outb[SCAP];
  int b = blockIdx.x;
  int bo = bucketOff[b], b1 = bucketOff[b + 1];
  int len = b1 - bo;
  int tid = threadIdx.x;
  int n0 = b << 7;
  if (tid < 128) cnt[tid] = 0;
  __syncthreads();
  for (int i = tid; i < len; i += 256) atomicAdd(&cnt[bucketed[bo + i] & 127], 1);
  __syncthreads();
  if (tid < 128) inc[tid] = cnt[tid];
  __syncthreads();
  for (int d = 1; d < 128; d <<= 1) {
    int v = 0;
    if (tid < 128 && tid >= d) v = inc[tid - d];
    __syncthreads();
    if (tid < 128) inc[tid] += v;
    __syncthreads();
  }
  if (tid < 128) {
    int off = inc[tid] - cnt[tid];
    cur[tid] = off;
    int node = n0 + tid;
    if (node < n) rs[node] = bo + off;
  }
  __syncthreads();
  if (len <= SCAP) {
    for (int i = tid; i < len; i += 256) {
      unsigned w = bucketed[bo + i];
      int p = atomicAdd(&cur[w & 127], 1);
      outb[p] = (unsigned short)(w >> 16);
    }
    __syncthreads();
    for (int i = tid; i < len; i += 256) ssrc[bo + i] = outb[i];
  } else {
    for (int i = tid; i < len; i += 256) {
      unsigned w = bucketed[bo + i];
      int p = atomicAdd(&cur[w & 127], 1);
      ssrc[bo + p] = (unsigned short)(w >> 16);
    }
  }
}

// ---------- conv: f32 -> packed bf16x2 ----------
__global__ __launch_bounds__(256) void conv_bf16(const float* __restrict__ x,
                                                 unsigned int* __restrict__ hb, int n64) {
  int i = blockIdx.x * 256 + threadIdx.x;
  if (i < n64) {
    float2 v = ((const float2*)x)[i];
    hb[i] = packbf(v.x, v.y);
  }
}

// ---------- W prep: split W into (hi, lo) bf16, transposed [col][k] ----------
__global__ __launch_bounds__(256) void prep_w(const float* __restrict__ W1,
                                              const float* __restrict__ W2,
                                              short* __restrict__ wt) {
  int idx = blockIdx.x * 256 + threadIdx.x;  // 3*2*16384
  if (idx >= 3 * 2 * 16384) return;
  int lm = idx >> 14;      // layer*2 + mat
  int e = idx & 16383;
  int k = e >> 7;
  int col = e & 127;
  int layer = lm >> 1, mat = lm & 1;
  const float* W = mat ? W2 : W1;
  float w = W[layer * 16384 + k * 128 + col];
  unsigned short h = (unsigned short)bf16rne(w);
  float hv = __uint_as_float((unsigned)h << 16);
  unsigned short lo = (unsigned short)bf16rne(w - hv);
  size_t base = (size_t)lm * 2 * 16384;
  wt[base + col * 128 + k] = (short)h;
  wt[base + 16384 + col * 128 + k] = (short)lo;
}

// ---------- aggregation: zb = hb_i + sum_{j->i} hb_j (f32 accum, bf16 out) ----------
__global__ __launch_bounds__(256) void gather_zb(const unsigned int* __restrict__ hb,
                                                 const int* __restrict__ rs,
                                                 const unsigned short* __restrict__ ssrc,
                                                 unsigned int* __restrict__ zb, int n) {
  int node = blockIdx.x * 4 + (threadIdx.x >> 6);
  if (node >= n) return;
  int lane = threadIdx.x & 63;
  int s0 = rs[node], s1 = rs[node + 1];
  unsigned v = hb[(size_t)node * 64 + lane];
  float ax = bflo(v), ay = bfhi(v);
  int t = s0;
  for (; t + 3 < s1; t += 4) {
    int sa = ssrc[t], sb = ssrc[t + 1], sc = ssrc[t + 2], sd = ssrc[t + 3];
    unsigned va = hb[(size_t)sa * 64 + lane];
    unsigned vb = hb[(size_t)sb * 64 + lane];
    unsigned vc = hb[(size_t)sc * 64 + lane];
    unsigned vd = hb[(size_t)sd * 64 + lane];
    ax += bflo(va) + bflo(vb) + bflo(vc) + bflo(vd);
    ay += bfhi(va) + bfhi(vb) + bfhi(vc) + bfhi(vd);
  }
  for (; t < s1; ++t) {
    unsigned vv = hb[(size_t)ssrc[t] * 64 + lane];
    ax += bflo(vv);
    ay += bfhi(vv);
  }
  zb[(size_t)node * 64 + lane] = packbf(ax, ay);
}

// ---------- MFMA MLP: hout = relu(z@W1+b1)@W2+b2 ----------
// 128 threads = 2 waves; BM=64 (wave owns 32 rows = 2x16 tiles).
// Wt layout per matmul: [part(hi,lo)][col][k] bf16.
__global__ __launch_bounds__(128, 2) void mlp_mfma(
    const unsigned int* __restrict__ zb,
    const short* __restrict__ Wt1, const short* __restrict__ Wt2,
    const float* __restrict__ b1, const float* __restrict__ b2,
    float* __restrict__ fout, unsigned short* __restrict__ hbout, int n) {
  __shared__ char hsb[64 * 256];  // 16KB swizzled bf16 h-tile
  int tid = threadIdx.x;
  int w = tid >> 6, lane = tid & 63;
  int lr = lane & 15, hi = lane >> 4;
  int node0 = blockIdx.x * 64;

  // A1 frags from global zb (bf16 rows)
  bf16x8 a[2][4];
#pragma unroll
  for (int t = 0; t < 2; ++t) {
    int row = node0 + w * 32 + t * 16 + lr;
    row = min(row, n - 1);
    const char* rp = (const char*)(zb + (size_t)row * 64);
#pragma unroll
    for (int ks = 0; ks < 4; ++ks)
      a[t][ks] = *(const bf16x8*)(rp + ks * 64 + hi * 16);
  }

  f32x4 acc[2][8];
#pragma unroll
  for (int ct = 0; ct < 8; ++ct) {
    float bb = b1[ct * 16 + lr];
    acc[0][ct] = (f32x4){bb, bb, bb, bb};
    acc[1][ct] = acc[0][ct];
  }

  // matmul1: z @ W1  (hi then lo part, both accumulate)
  const char* wbase1 = (const char*)Wt1 + ((size_t)lr * 128 + hi * 8) * 2;
#pragma unroll
  for (int p = 0; p < 2; ++p) {
    const char* wp = wbase1 + p * 32768;
#pragma unroll
    for (int ct = 0; ct < 8; ++ct) {
#pragma unroll
      for (int ks = 0; ks < 4; ++ks) {
        bf16x8 b = *(const bf16x8*)(wp + ct * 4096 + ks * 64);
        acc[0][ct] = __builtin_amdgcn_mfma_f32_16x16x32_bf16(a[0][ks], b, acc[0][ct], 0, 0, 0);
        acc[1][ct] = __builtin_amdgcn_mfma_f32_16x16x32_bf16(a[1][ks], b, acc[1][ct], 0, 0, 0);
      }
    }
  }

  // relu -> swizzled LDS bf16 (transpose C-layout -> A-frag layout)
#pragma unroll
  for (int t = 0; t < 2; ++t)
#pragma unroll
    for (int ct = 0; ct < 8; ++ct)
#pragma unroll
      for (int r = 0; r < 4; ++r) {
        int row = w * 32 + t * 16 + hi * 4 + r;
        int col = ct * 16 + lr;
        float v = fmaxf(acc[t][ct][r], 0.f);
        int byte = (row * 256 + col * 2) ^ ((row & 7) << 4);
        *(unsigned short*)&hsb[byte] = (unsigned short)bf16rne(v);
      }
  __syncthreads();

  // A2 frags from LDS
  bf16x8 a2[2][4];
#pragma unroll
  for (int t = 0; t < 2; ++t) {
    int row = w * 32 + t * 16 + lr;
    int xr = (row & 7) << 4;
#pragma unroll
    for (int ks = 0; ks < 4; ++ks)
      a2[t][ks] = *(const bf16x8*)&hsb[(row * 256 + ks * 64 + hi * 16) ^ xr];
  }

#pragma unroll
  for (int ct = 0; ct < 8; ++ct) {
    float bb = b2[ct * 16 + lr];
    acc[0][ct] = (f32x4){bb, bb, bb, bb};
    acc[1][ct] = acc[0][ct];
  }

  // matmul2: h @ W2
  const char* wbase2 = (const char*)Wt2 + ((size_t)lr * 128 + hi * 8) * 2;
#pragma unroll
  for (int p = 0; p < 2; ++p) {
    const char* wp = wbase2 + p * 32768;
#pragma unroll
    for (int ct = 0; ct < 8; ++ct) {
#pragma unroll
      for (int ks = 0; ks < 4; ++ks) {
        bf16x8 b = *(const bf16x8*)(wp + ct * 4096 + ks * 64);
        acc[0][ct] = __builtin_amdgcn_mfma_f32_16x16x32_bf16(a2[0][ks], b, acc[0][ct], 0, 0, 0);
        acc[1][ct] = __builtin_amdgcn_mfma_f32_16x16x32_bf16(a2[1][ks], b, acc[1][ct], 0, 0, 0);
      }
    }
  }

  // store: C layout col=lane&15, row=(lane>>4)*4+reg
#pragma unroll
  for (int t = 0; t < 2; ++t)
#pragma unroll
    for (int ct = 0; ct < 8; ++ct)
#pragma unroll
      for (int r = 0; r < 4; ++r) {
        int node = node0 + w * 32 + t * 16 + hi * 4 + r;
        if (node < n) {
          int col = ct * 16 + lr;
          float v = acc[t][ct][r];
          if (fout) fout[(size_t)node * DD + col] = v;
          if (hbout) hbout[(size_t)node * DD + col] = (unsigned short)bf16rne(v);
        }
      }
}

// ---------- classifier ----------
__global__ __launch_bounds__(256) void classifier_k(const float* __restrict__ h,
                                                    const float* __restrict__ Wc,
                                                    const float* __restrict__ bc,
                                                    float* __restrict__ out, int n) {
  __shared__ float wcs[DD * 16];
  for (int i = threadIdx.x; i < DD * 16; i += 256) wcs[i] = Wc[i];
  __syncthreads();
  int t = blockIdx.x * 256 + threadIdx.x;
  int node = t >> 4, c = t & 15;
  if (node >= n) return;
  float acc = bc[c];
  const float* hr = h + (size_t)node * DD;
#pragma unroll 8
  for (int k = 0; k < DD; ++k) acc += hr[k] * wcs[k * 16 + c];
  out[(size_t)node * 16 + c] = acc;
}

extern "C" void kernel_launch(void* const* d_in, const int* in_sizes, int n_in,
                              void* d_out, int out_size, void* d_ws, size_t ws_size,
                              hipStream_t stream) {
  const float* x = (const float*)d_in[0];
  const int* ei = (const int*)d_in[1];
  const float* W1 = (const float*)d_in[2];
  const float* b1 = (const float*)d_in[3];
  const float* W2 = (const float*)d_in[4];
  const float* b2 = (const float*)d_in[5];
  const float* Wc = (const float*)d_in[6];
  const float* bc = (const float*)d_in[7];

  const int N = in_sizes[0] / DD;
  const int E = in_sizes[1] / 2;
  const int* src = ei;
  const int* dst = ei + E;
  const int NB = (N + 127) >> 7;

  float* outp = (float*)d_out;
  float* h_final = outp;
  float* logits = outp + (size_t)N * DD;

  char* ws = (char*)d_ws;
  size_t off = 0;
  auto alloc = [&](size_t bytes) {
    char* p = ws + off;
    off = (off + bytes + 255) & ~(size_t)255;
    return p;
  };
  unsigned int* zb = (unsigned int*)alloc((size_t)N * 64 * 4);   // packed bf16 z
  unsigned int* hb = (unsigned int*)alloc((size_t)N * 64 * 4);   // packed bf16 h
  short* wt = (short*)alloc((size_t)3 * 2 * 2 * 16384 * 2);      // split transposed W
  int* bucketCount = (int*)alloc(NBMAX * 4);
  int* bucketOff = (int*)alloc((NBMAX + 1) * 4);
  int* gCursor = (int*)alloc(NBMAX * 4);
  int* rs = (int*)alloc((size_t)(N + 1) * 4);
  unsigned int* bucketed = (unsigned int*)alloc((size_t)E * 4);
  unsigned short* ssrc = (unsigned short*)alloc((size_t)E * 2);

  const int gEdge = (E + CHUNK - 1) / CHUNK;
  const int gGather = (N + 3) / 4;
  const int gMlp = (N + 63) / 64;

  // CSR build
  hipMemsetAsync(bucketCount, 0, NBMAX * 4, stream);
  s1_hist<<<gEdge, 256, 0, stream>>>(dst, bucketCount, E);
  s2_scan<<<1, 256, 0, stream>>>(bucketCount, bucketOff, gCursor, rs, NB, N, E);
  s3_scatter<<<gEdge, 256, 0, stream>>>(src, dst, gCursor, bucketed, E, NB);
  s4_fill<<<NB, 256, 0, stream>>>(bucketed, bucketOff, rs, ssrc, N);

  // weight prep + x -> bf16
  prep_w<<<(3 * 2 * 16384 + 255) / 256, 256, 0, stream>>>(W1, W2, wt);
  conv_bf16<<<(N * 64 + 255) / 256, 256, 0, stream>>>(x, hb, N * 64);

  auto WT = [&](int layer, int mat) { return wt + ((size_t)(layer * 2 + mat)) * 2 * 16384; };

  // layer 0
  gather_zb<<<gGather, 256, 0, stream>>>(hb, rs, ssrc, zb, N);
  mlp_mfma<<<gMlp, 128, 0, stream>>>(zb, WT(0, 0), WT(0, 1), b1, b2,
                                     nullptr, (unsigned short*)hb, N);
  // layer 1
  gather_zb<<<gGather, 256, 0, stream>>>(hb, rs, ssrc, zb, N);
  mlp_mfma<<<gMlp, 128, 0, stream>>>(zb, WT(1, 0), WT(1, 1), b1 + DD, b2 + DD,
                                     nullptr, (unsigned short*)hb, N);
  // layer 2 -> f32 output
  gather_zb<<<gGather, 256, 0, stream>>>(hb, rs, ssrc, zb, N);
  mlp_mfma<<<gMlp, 128, 0, stream>>>(zb, WT(2, 0), WT(2, 1), b1 + 2 * DD, b2 + 2 * DD,
                                     h_final, nullptr, N);

  classifier_k<<<(N * 16 + 255) / 256, 256, 0, stream>>>(h_final, Wc, bc, logits, N);
}